// Round 1
// baseline (201.501 us; speedup 1.0000x reference)
//
#include <hip/hip_runtime.h>

#define SEQ    512
#define CHUNKS (SEQ / 4)   // 128 float4 per row
#define PF     8           // prefetch depth in float4 (128 B/lane in flight)

// One recurrence step:
//   d = h - xt; t = tanh(s0*d); u = c0 + c1*t + c2*t^2; g = sigmoid(u); h' = g*d + xt
__device__ __forceinline__ float stepfn(float h, float xt,
                                        float s0, float c0, float c1, float c2) {
    float d = h - xt;
    float x = s0 * d;
    // tanh(x) = 1 - 2/(1 + exp(2x)); exp(2x) = exp2(x * 2*log2(e))
    float e  = __builtin_amdgcn_exp2f(x * 2.8853900817779268f);
    float t  = fmaf(-2.0f, __builtin_amdgcn_rcpf(e + 1.0f), 1.0f);
    float u  = fmaf(t, fmaf(c2, t, c1), c0);
    // sigmoid(u) = 1/(1 + exp(-u))
    float e2 = __builtin_amdgcn_exp2f(u * -1.4426950408889634f);
    float g  = __builtin_amdgcn_rcpf(e2 + 1.0f);
    return fmaf(g, d, xt);
}

__global__ __launch_bounds__(256) void scan_kernel(
    const float* __restrict__ X,
    const float* __restrict__ W1,
    const float* __restrict__ W2,
    const float* __restrict__ bias,
    const float* __restrict__ Wzero,
    const float* __restrict__ Wsign,
    float* __restrict__ out, int batch)
{
    int i = blockIdx.x * blockDim.x + threadIdx.x;
    if (i >= batch) return;

    // Scalar parameter prep (amortized over 511 steps).
    // softmax([w0,w1])[0] = 1/(1+exp(w1-w0)); sel_diff = [a1-a2, -(a1-a2)]
    float a1 = 1.0f / (1.0f + __expf(W1[1] - W1[0]));
    float a2 = 1.0f / (1.0f + __expf(W2[1] - W2[0]));
    float s0 = a1 - a2;
    float wz = Wzero[0];
    float c0 = bias[0] + wz;      // u = (b + wz) + ws*t - 2*wz*t^2
    float c1 = Wsign[0];
    float c2 = -2.0f * wz;

    const float4* row = (const float4*)(X + (size_t)i * SEQ);

    // 8-deep rotating prefetch buffer: loads for chunk n+PF issued while
    // computing chunk n (4 steps/chunk ~ 200 cyc; covers ~900 cyc HBM latency
    // with 1 wave/SIMD — no TLP available, pure ILP hiding).
    float4 buf[PF];
    #pragma unroll
    for (int k = 0; k < PF; ++k) buf[k] = row[k];

    float h = 0.0f;
    for (int base = 0; base < CHUNKS; base += PF) {
        #pragma unroll
        for (int k = 0; k < PF; ++k) {
            float4 v = buf[k];
            int n = base + PF + k;
            if (n < CHUNKS) buf[k] = row[n];   // uniform predicate (scalar branch)
            if (k == 0 && base == 0) h = v.x;  // h0 = X[:,0]
            else h = stepfn(h, v.x, s0, c0, c1, c2);
            h = stepfn(h, v.y, s0, c0, c1, c2);
            h = stepfn(h, v.z, s0, c0, c1, c2);
            h = stepfn(h, v.w, s0, c0, c1, c2);
        }
    }
    out[i] = h;
}

extern "C" void kernel_launch(void* const* d_in, const int* in_sizes, int n_in,
                              void* d_out, int out_size, void* d_ws, size_t ws_size,
                              hipStream_t stream) {
    const float* X    = (const float*)d_in[0];
    const float* W1   = (const float*)d_in[1];
    const float* W2   = (const float*)d_in[2];
    const float* bias = (const float*)d_in[3];
    const float* Wz   = (const float*)d_in[4];
    const float* Wsg  = (const float*)d_in[5];
    float* out = (float*)d_out;

    int batch = in_sizes[0] / SEQ;
    dim3 block(256);
    dim3 grid((batch + block.x - 1) / block.x);
    scan_kernel<<<grid, block, 0, stream>>>(X, W1, W2, bias, Wz, Wsg, out, batch);
}